// Round 4
// baseline (729.907 us; speedup 1.0000x reference)
//
#include <hip/hip_runtime.h>
#include <hip/hip_bf16.h>
#include <cstdint>
#include <cstddef>

// Seq2seq LSTM (enc 64 steps + dec 50 steps), B=8192, H=128, DIN=DOUT=8.
// Persistent kernel: 256 blocks x 512 threads, 32 batch rows/block, all 114
// steps in one launch. Recurrent matmul via split-bf16 MFMA (hi/lo
// compensation => ~f32 accuracy): W*h ~= Whi*hhi + Whi*hlo + Wlo*hhi.
// Weights (Whh|Wih|b concat, K padded to 160) persist in VGPRs as MFMA
// B-fragments (40 frags = 160 VGPR/wave); c-state lives in C-frag registers;
// h exchanged per step via double-buffered LDS (bf16 hi/lo).
//
// R1 fix: prologue zero-fill raced with the bias-column / x_0 special writes
// (no barrier between them) -> nondeterministic loss of bias/inputs.
// Now: zero-fill, __syncthreads, special writes, __syncthreads, main loop.
// R2/R3: identical resubmits (benches died on GPU acquisition, fix untested).

#define BTOT   8192
#define TENC   64
#define DIN    8
#define HU     128
#define DOUTN  8
#define NSTEPS 50
#define NG     512          // 4*H gates
#define KP     160          // padded K: 128 h + 8 inp + 1 bias + pad
#define KSTR   168          // LDS row stride (bf16 elems) -> 2-way-free banks
#define ROWS   32           // batch rows per block

typedef __attribute__((ext_vector_type(8))) short short8;
typedef __attribute__((ext_vector_type(4))) float f32x4;

__device__ __forceinline__ float fsigm(float v) {
  return __builtin_amdgcn_rcpf(1.f + __expf(-v));
}
__device__ __forceinline__ float ftanh(float v) {
  // tanh(x) = 1 - 2/(exp(2x)+1); saturates correctly at +/-inf
  return 1.f - 2.f * __builtin_amdgcn_rcpf(1.f + __expf(2.f * v));
}
__device__ __forceinline__ unsigned short f2bf(float v) {
  union { __hip_bfloat16 b; unsigned short u; } cv;
  cv.b = __float2bfloat16(v);
  return cv.u;
}
__device__ __forceinline__ float bf2f(unsigned short u) {
  union { __hip_bfloat16 b; unsigned short u; } cv;
  cv.u = u;
  return __bfloat162float(cv.b);
}
__device__ __forceinline__ void split2(float v, unsigned short& hi, unsigned short& lo) {
  hi = f2bf(v);
  lo = f2bf(v - bf2f(hi));
}

// Build Wcat[phase][hl][512][KP] (bf16 hi/lo) in workspace.
// Wcat[g][k]: k<128 -> Whh[g][k]; 128<=k<136 -> Wih[g][k-128]; k==136 -> b[g]; else 0.
__global__ void prep_weights(const float* __restrict__ enc_Wih,
                             const float* __restrict__ enc_Whh,
                             const float* __restrict__ enc_b,
                             const float* __restrict__ dec_Wih,
                             const float* __restrict__ dec_Whh,
                             const float* __restrict__ dec_b,
                             unsigned short* __restrict__ wcat) {
  int idx = blockIdx.x * blockDim.x + threadIdx.x;
  int total = 2 * NG * KP;
  if (idx >= total) return;
  int k  = idx % KP;
  int g  = (idx / KP) % NG;
  int ph = idx / (KP * NG);
  const float* Wih = ph ? dec_Wih : enc_Wih;
  const float* Whh = ph ? dec_Whh : enc_Whh;
  const float* bb  = ph ? dec_b   : enc_b;
  float w = 0.f;
  if (k < HU)            w = Whh[g * HU + k];
  else if (k < HU + DIN) w = Wih[g * DIN + (k - HU)];
  else if (k == HU + DIN) w = bb[g];
  unsigned short hi, lo;
  split2(w, hi, lo);
  wcat[((size_t)(ph * 2 + 0) * NG + g) * KP + k] = hi;
  wcat[((size_t)(ph * 2 + 1) * NG + g) * KP + k] = lo;
}

__global__ __launch_bounds__(512, 2)
void lstm_fused(const float* __restrict__ x,
                const float* __restrict__ drop_u,
                const float* __restrict__ out_W,
                const float* __restrict__ out_b,
                const unsigned short* __restrict__ wcat,
                float* __restrict__ out) {
  __shared__ unsigned short h_hi[2][ROWS][KSTR];
  __shared__ unsigned short h_lo[2][ROWS][KSTR];
  __shared__ unsigned short hd_hi[ROWS][KSTR];
  __shared__ unsigned short hd_lo[ROWS][KSTR];
  __shared__ unsigned short ow_lds[2][16][KP];   // out_W|out_b, hi/lo
  __shared__ float mask_lds[ROWS][HU + 2];

  const int tid = threadIdx.x;
  const int wv  = tid >> 6;            // wave 0..7: owns units wv*16..wv*16+16
  const int l15 = tid & 15;            // lane&15
  const int l4  = (tid >> 4) & 3;      // lane>>4
  const int rb  = blockIdx.x * ROWS;

  // ---------------- prologue: phase 1 — bulk zero/deterministic fills ------
  for (int i = tid; i < 2 * ROWS * KSTR; i += 512) {
    (&h_hi[0][0][0])[i] = 0; (&h_lo[0][0][0])[i] = 0;
  }
  for (int i = tid; i < ROWS * KSTR; i += 512) {
    (&hd_hi[0][0])[i] = 0; (&hd_lo[0][0])[i] = 0;
  }
  // output projection weights -> LDS (hi/lo); k==128 carries out_b.
  // (each element written exactly once with its final value — no conflict)
  for (int i = tid; i < 16 * KP; i += 512) {
    int o = i / KP, k = i % KP;
    float w = 0.f;
    if (o < DOUTN) {
      if (k < HU)       w = out_W[o * HU + k];
      else if (k == HU) w = out_b[o];
    }
    unsigned short hi, lo;
    split2(w, hi, lo);
    ow_lds[0][o][k] = hi; ow_lds[1][o][k] = lo;
  }

  __syncthreads();  // R1 FIX: zero-fill fully done before special overwrites

  // ---------------- prologue: phase 2 — special-value overwrites ----------
  // bias-multiplier columns = 1.0 (bf16 0x3F80)
  if (tid < 2 * ROWS) h_hi[tid >> 5][tid & 31][HU + DIN] = 0x3F80;
  if (tid < ROWS)     hd_hi[tid][HU] = 0x3F80;
  // stage x_0 into buffer 0 input columns
  if (tid < ROWS * DIN) {
    int r = tid >> 3, i = tid & 7;
    float v = x[((size_t)(rb + r) * TENC + 0) * DIN + i];
    unsigned short hi, lo;
    split2(v, hi, lo);
    h_hi[0][r][HU + i] = hi; h_lo[0][r][HU + i] = lo;
  }

  // ---------------- persistent B fragments (encoder phase) ----------------
  short8 Bf[4][5][2];
  {
    const unsigned short* base = wcat;  // phase 0
#pragma unroll
    for (int gt = 0; gt < 4; ++gt)
#pragma unroll
      for (int kt = 0; kt < 5; ++kt) {
        int g = gt * HU + wv * 16 + l15;
        int k = kt * 32 + l4 * 8;
        Bf[gt][kt][0] = *(const short8*)(base + ((size_t)(0 * NG + g)) * KP + k);
        Bf[gt][kt][1] = *(const short8*)(base + ((size_t)(1 * NG + g)) * KP + k);
      }
  }

  float c_st[8];
#pragma unroll
  for (int i = 0; i < 8; ++i) c_st[i] = 0.f;

  auto stage_mask = [&](int sidx) {
    const float* src = drop_u + ((size_t)sidx * BTOT + rb) * HU
                     + (size_t)(tid >> 4) * HU + (size_t)(tid & 15) * 8;
    float4 a  = ((const float4*)src)[0];
    float4 b2 = ((const float4*)src)[1];
    float* dst = &mask_lds[tid >> 4][(tid & 15) * 8];
    dst[0] = (a.x  >= 0.2f) ? 1.25f : 0.f;
    dst[1] = (a.y  >= 0.2f) ? 1.25f : 0.f;
    dst[2] = (a.z  >= 0.2f) ? 1.25f : 0.f;
    dst[3] = (a.w  >= 0.2f) ? 1.25f : 0.f;
    dst[4] = (b2.x >= 0.2f) ? 1.25f : 0.f;
    dst[5] = (b2.y >= 0.2f) ? 1.25f : 0.f;
    dst[6] = (b2.z >= 0.2f) ? 1.25f : 0.f;
    dst[7] = (b2.w >= 0.2f) ? 1.25f : 0.f;
  };

  __syncthreads();  // prologue complete (specials visible to all waves)

  // ---------------- 114-step recurrence ----------------
#pragma unroll 1
  for (int s = 0; s < TENC + NSTEPS; ++s) {
    const int cur = s & 1, nxt = cur ^ 1;
    const bool dec = (s >= TENC);

    if (s == TENC) {  // switch to decoder weights
      const unsigned short* base = wcat + (size_t)2 * NG * KP;
#pragma unroll
      for (int gt = 0; gt < 4; ++gt)
#pragma unroll
        for (int kt = 0; kt < 5; ++kt) {
          int g = gt * HU + wv * 16 + l15;
          int k = kt * 32 + l4 * 8;
          Bf[gt][kt][0] = *(const short8*)(base + ((size_t)(0 * NG + g)) * KP + k);
          Bf[gt][kt][1] = *(const short8*)(base + ((size_t)(1 * NG + g)) * KP + k);
        }
    }

#pragma unroll
    for (int rt = 0; rt < 2; ++rt) {
      // A fragments: rows rt*16..+16, all K (h|inp|1|pad), hi/lo
      short8 Ah[5], Al[5];
      {
        int r = rt * 16 + l15;
#pragma unroll
        for (int kt = 0; kt < 5; ++kt) {
          Ah[kt] = *(const short8*)&h_hi[cur][r][kt * 32 + l4 * 8];
          Al[kt] = *(const short8*)&h_lo[cur][r][kt * 32 + l4 * 8];
        }
      }
      f32x4 acc[4];
#pragma unroll
      for (int gt = 0; gt < 4; ++gt) {
        acc[gt] = (f32x4){0.f, 0.f, 0.f, 0.f};
#pragma unroll
        for (int kt = 0; kt < 5; ++kt) {
          acc[gt] = __builtin_amdgcn_mfma_f32_16x16x32_bf16(Al[kt], Bf[gt][kt][0], acc[gt], 0, 0, 0);
          acc[gt] = __builtin_amdgcn_mfma_f32_16x16x32_bf16(Ah[kt], Bf[gt][kt][1], acc[gt], 0, 0, 0);
          acc[gt] = __builtin_amdgcn_mfma_f32_16x16x32_bf16(Ah[kt], Bf[gt][kt][0], acc[gt], 0, 0, 0);
        }
      }
      // elementwise LSTM cell for this row-tile (wave-local: all 4 gates here)
      const int uu = wv * 16 + l15;
#pragma unroll
      for (int j = 0; j < 4; ++j) {
        float iv = fsigm(acc[0][j]);
        float fv = fsigm(acc[1][j]);
        float gv = ftanh(acc[2][j]);
        float ov = fsigm(acc[3][j]);
        float cn = fv * c_st[rt * 4 + j] + iv * gv;
        c_st[rt * 4 + j] = cn;
        float hv = ov * ftanh(cn);
        int rr = rt * 16 + l4 * 4 + j;
        unsigned short hi, lo;
        split2(hv, hi, lo);
        h_hi[nxt][rr][uu] = hi; h_lo[nxt][rr][uu] = lo;
        if (dec) {
          float hd = hv * mask_lds[rr][uu];
          unsigned short dhi, dlo;
          split2(hd, dhi, dlo);
          hd_hi[rr][uu] = dhi; hd_lo[rr][uu] = dlo;
        }
      }
    }

    if (!dec) {
      // stage next input column: x_{s+1}, or x_63 (= decoder init) at s==63
      int tn = (s + 1 < TENC) ? (s + 1) : (TENC - 1);
      if (tid < ROWS * DIN) {
        int r = tid >> 3, i = tid & 7;
        float v = x[((size_t)(rb + r) * TENC + tn) * DIN + i];
        unsigned short hi, lo;
        split2(v, hi, lo);
        h_hi[nxt][r][HU + i] = hi; h_lo[nxt][r][HU + i] = lo;
      }
      if (s == TENC - 1) stage_mask(0);
      __syncthreads();                       // 1 barrier per encoder step
    } else {
      __syncthreads();                       // hd complete
      if (wv < 2) {                          // y = hd @ outW^T + out_b
        const int rt = wv;
        short8 Ah2[5], Al2[5];
        int r = rt * 16 + l15;
#pragma unroll
        for (int kt = 0; kt < 5; ++kt) {
          Ah2[kt] = *(const short8*)&hd_hi[r][kt * 32 + l4 * 8];
          Al2[kt] = *(const short8*)&hd_lo[r][kt * 32 + l4 * 8];
        }
        f32x4 ay = (f32x4){0.f, 0.f, 0.f, 0.f};
#pragma unroll
        for (int kt = 0; kt < 5; ++kt) {
          short8 bh = *(const short8*)&ow_lds[0][l15][kt * 32 + l4 * 8];
          short8 bl = *(const short8*)&ow_lds[1][l15][kt * 32 + l4 * 8];
          ay = __builtin_amdgcn_mfma_f32_16x16x32_bf16(Al2[kt], bh, ay, 0, 0, 0);
          ay = __builtin_amdgcn_mfma_f32_16x16x32_bf16(Ah2[kt], bl, ay, 0, 0, 0);
          ay = __builtin_amdgcn_mfma_f32_16x16x32_bf16(Ah2[kt], bh, ay, 0, 0, 0);
        }
        if (l15 < DOUTN) {
#pragma unroll
          for (int j = 0; j < 4; ++j) {
            int rr = rt * 16 + l4 * 4 + j;
            float yv = ay[j];
            out[((size_t)(rb + rr) * NSTEPS + (s - TENC)) * DOUTN + l15] = yv;
            unsigned short hi, lo;
            split2(yv, hi, lo);                 // y feeds next step's input cols
            h_hi[nxt][rr][HU + l15] = hi; h_lo[nxt][rr][HU + l15] = lo;
          }
        }
      }
      if (s + 1 < TENC + NSTEPS) stage_mask(s + 1 - TENC);
      __syncthreads();                       // inputs/mask ready for next step
    }
  }
}

extern "C" void kernel_launch(void* const* d_in, const int* in_sizes, int n_in,
                              void* d_out, int out_size, void* d_ws, size_t ws_size,
                              hipStream_t stream) {
  const float* x       = (const float*)d_in[0];
  const float* drop_u  = (const float*)d_in[1];
  const float* enc_Wih = (const float*)d_in[2];
  const float* enc_Whh = (const float*)d_in[3];
  const float* enc_b   = (const float*)d_in[4];
  const float* dec_Wih = (const float*)d_in[5];
  const float* dec_Whh = (const float*)d_in[6];
  const float* dec_b   = (const float*)d_in[7];
  const float* out_W   = (const float*)d_in[8];
  const float* out_b   = (const float*)d_in[9];

  unsigned short* wcat = (unsigned short*)d_ws;   // [2 phase][2 hl][512][KP] bf16

  int prep_total = 2 * NG * KP;
  prep_weights<<<(prep_total + 255) / 256, 256, 0, stream>>>(
      enc_Wih, enc_Whh, enc_b, dec_Wih, dec_Whh, dec_b, wcat);

  lstm_fused<<<256, 512, 0, stream>>>(x, drop_u, out_W, out_b, wcat, (float*)d_out);
}